// Round 5
// baseline (173.268 us; speedup 1.0000x reference)
//
#include <hip/hip_runtime.h>
#include <math.h>

#define H 128
#define BLK 256
#define MMR 32  // rows per block in the GEMM pass (16 KB LDS)

__device__ inline float fast_tanh(float x) {
    return 1.0f - 2.0f / (__expf(2.0f * x) + 1.0f);
}

// ---------- CSR build ----------
__global__ void count_kernel(const int* __restrict__ dst, int* __restrict__ cnt, int E) {
    int e = blockIdx.x * blockDim.x + threadIdx.x;
    if (e < E) atomicAdd(&cnt[dst[e]], 1);
}

__global__ void blocksum_kernel(const int* __restrict__ cnt, int* __restrict__ bsum, int n) {
    __shared__ int tmp[BLK];
    int i = blockIdx.x * BLK + threadIdx.x;
    tmp[threadIdx.x] = (i < n) ? cnt[i] : 0;
    __syncthreads();
    for (int d = BLK >> 1; d; d >>= 1) {
        if (threadIdx.x < d) tmp[threadIdx.x] += tmp[threadIdx.x + d];
        __syncthreads();
    }
    if (threadIdx.x == 0) bsum[blockIdx.x] = tmp[0];
}

__global__ void scanpart_kernel(int* bsum, int nb) {
    __shared__ int tmp[BLK];
    int t = threadIdx.x;
    int v = (t < nb) ? bsum[t] : 0;
    tmp[t] = v;
    __syncthreads();
    for (int d = 1; d < BLK; d <<= 1) {
        int add = (t >= d) ? tmp[t - d] : 0;
        __syncthreads();
        tmp[t] += add;
        __syncthreads();
    }
    if (t < nb) bsum[t] = tmp[t] - v;  // exclusive
}

__global__ void offsets_kernel(const int* __restrict__ cnt, const int* __restrict__ bsum,
                               int* __restrict__ off, int n, int E) {
    __shared__ int tmp[BLK];
    int t = threadIdx.x;
    int i = blockIdx.x * BLK + t;
    int v = (i < n) ? cnt[i] : 0;
    tmp[t] = v;
    __syncthreads();
    for (int d = 1; d < BLK; d <<= 1) {
        int add = (t >= d) ? tmp[t - d] : 0;
        __syncthreads();
        tmp[t] += add;
        __syncthreads();
    }
    if (i < n) off[i] = tmp[t] - v + bsum[blockIdx.x];
    if (i == 0) off[n] = E;
}

__global__ void fill_kernel(const int* __restrict__ src, const int* __restrict__ dst,
                            const int* __restrict__ rid, const int* __restrict__ off,
                            int* __restrict__ cursor, int2* __restrict__ epack, int E) {
    int e = blockIdx.x * blockDim.x + threadIdx.x;
    if (e >= E) return;
    int d = dst[e];
    int pos = atomicAdd(&cursor[d], 1);
    epack[off[d] + pos] = make_int2(src[e], rid[e]);
}

// ---------- fused gather: 8 edges in flight per wave ----------
// wave = 8 groups x 8 lanes; each group owns one edge (16 floats per lane).
// Per-group online softmax state, exact rescaled merge at the end.
__global__ void gather_kernel(const float* __restrict__ ent, const float* __restrict__ rel,
                              const int2* __restrict__ epack, const int* __restrict__ off,
                              float* __restrict__ neigh, int n_nodes) {
    int lane = threadIdx.x & 63;
    int node = blockIdx.x * (blockDim.x >> 6) + (threadIdx.x >> 6);
    if (node >= n_nodes) return;
    int beg = off[node];
    int deg = off[node + 1] - beg;
    int g = lane >> 3;   // group 0..7
    int gl = lane & 7;   // lane within group: float4s gl*4 .. gl*4+3

    const float4* crow = (const float4*)(ent + (size_t)node * H);
    float4 c0 = crow[gl * 4 + 0], c1 = crow[gl * 4 + 1];
    float4 c2 = crow[gl * 4 + 2], c3 = crow[gl * 4 + 3];

    float m = -3.0e38f, s = 0.0f;
    float4 A0 = make_float4(0.f, 0.f, 0.f, 0.f), A1 = A0, A2 = A0, A3 = A0;

    for (int base = 0; base < deg; base += 64) {
        int chunk = min(64, deg - base);
        int2 my = make_int2(0, 0);
        if (lane < chunk) my = epack[beg + base + lane];
        int iters = (chunk + 7) >> 3;
        for (int i = 0; i < iters; ++i) {
            int k = i * 8 + g;           // this group's edge
            bool valid = k < chunk;
            int kk = valid ? k : 0;
            int sv = __shfl(my.x, kk, 64);
            int rv = __shfl(my.y, kk, 64);
            if (valid) {
                const float4* ar = (const float4*)(ent + (size_t)sv * H);
                const float4* br = (const float4*)(rel + (size_t)rv * H);
                float4 a0 = ar[gl * 4 + 0], a1 = ar[gl * 4 + 1];
                float4 a2 = ar[gl * 4 + 2], a3 = ar[gl * 4 + 3];
                float4 b0 = br[gl * 4 + 0], b1 = br[gl * 4 + 1];
                float4 b2 = br[gl * 4 + 2], b3 = br[gl * 4 + 3];
                float4 q0, q1, q2, q3;
                q0.x = a0.x + b0.x; q0.y = a0.y + b0.y; q0.z = a0.z + b0.z; q0.w = a0.w + b0.w;
                q1.x = a1.x + b1.x; q1.y = a1.y + b1.y; q1.z = a1.z + b1.z; q1.w = a1.w + b1.w;
                q2.x = a2.x + b2.x; q2.y = a2.y + b2.y; q2.z = a2.z + b2.z; q2.w = a2.w + b2.w;
                q3.x = a3.x + b3.x; q3.y = a3.y + b3.y; q3.z = a3.z + b3.z; q3.w = a3.w + b3.w;
                float p = q0.x * c0.x + q0.y * c0.y + q0.z * c0.z + q0.w * c0.w
                        + q1.x * c1.x + q1.y * c1.y + q1.z * c1.z + q1.w * c1.w
                        + q2.x * c2.x + q2.y * c2.y + q2.z * c2.z + q2.w * c2.w
                        + q3.x * c3.x + q3.y * c3.y + q3.z * c3.z + q3.w * c3.w;
                // reduce within the 8-lane group
                p += __shfl_xor(p, 1, 64);
                p += __shfl_xor(p, 2, 64);
                p += __shfl_xor(p, 4, 64);
                if (p > m) {
                    float f = __expf(m - p);
                    s *= f;
                    A0.x *= f; A0.y *= f; A0.z *= f; A0.w *= f;
                    A1.x *= f; A1.y *= f; A1.z *= f; A1.w *= f;
                    A2.x *= f; A2.y *= f; A2.z *= f; A2.w *= f;
                    A3.x *= f; A3.y *= f; A3.z *= f; A3.w *= f;
                    m = p;
                }
                float w = __expf(p - m);
                s += w;
                A0.x += q0.x * w; A0.y += q0.y * w; A0.z += q0.z * w; A0.w += q0.w * w;
                A1.x += q1.x * w; A1.y += q1.y * w; A1.z += q1.z * w; A1.w += q1.w * w;
                A2.x += q2.x * w; A2.y += q2.y * w; A2.z += q2.z * w; A2.w += q2.w * w;
                A3.x += q3.x * w; A3.y += q3.y * w; A3.z += q3.z * w; A3.w += q3.w * w;
            }
        }
    }

    // merge the 8 group states (exact, rescaled); empty groups have m=-3e38,s=0
    #pragma unroll
    for (int xo = 8; xo <= 32; xo <<= 1) {
        float om = __shfl_xor(m, xo, 64);
        float os = __shfl_xor(s, xo, 64);
        float4 o0, o1, o2, o3;
        o0.x = __shfl_xor(A0.x, xo, 64); o0.y = __shfl_xor(A0.y, xo, 64);
        o0.z = __shfl_xor(A0.z, xo, 64); o0.w = __shfl_xor(A0.w, xo, 64);
        o1.x = __shfl_xor(A1.x, xo, 64); o1.y = __shfl_xor(A1.y, xo, 64);
        o1.z = __shfl_xor(A1.z, xo, 64); o1.w = __shfl_xor(A1.w, xo, 64);
        o2.x = __shfl_xor(A2.x, xo, 64); o2.y = __shfl_xor(A2.y, xo, 64);
        o2.z = __shfl_xor(A2.z, xo, 64); o2.w = __shfl_xor(A2.w, xo, 64);
        o3.x = __shfl_xor(A3.x, xo, 64); o3.y = __shfl_xor(A3.y, xo, 64);
        o3.z = __shfl_xor(A3.z, xo, 64); o3.w = __shfl_xor(A3.w, xo, 64);
        float M = fmaxf(m, om);
        float fs = __expf(m - M), fo = __expf(om - M);
        s = s * fs + os * fo;
        A0.x = A0.x * fs + o0.x * fo; A0.y = A0.y * fs + o0.y * fo;
        A0.z = A0.z * fs + o0.z * fo; A0.w = A0.w * fs + o0.w * fo;
        A1.x = A1.x * fs + o1.x * fo; A1.y = A1.y * fs + o1.y * fo;
        A1.z = A1.z * fs + o1.z * fo; A1.w = A1.w * fs + o1.w * fo;
        A2.x = A2.x * fs + o2.x * fo; A2.y = A2.y * fs + o2.y * fo;
        A2.z = A2.z * fs + o2.z * fo; A2.w = A2.w * fs + o2.w * fo;
        A3.x = A3.x * fs + o3.x * fo; A3.y = A3.y * fs + o3.y * fo;
        A3.z = A3.z * fs + o3.z * fo; A3.w = A3.w * fs + o3.w * fo;
        m = M;
    }
    float inv = (s > 0.0f) ? 1.0f / s : 0.0f;
    if (g == 0) {
        float4* outr = (float4*)(neigh + (size_t)node * H);
        outr[gl * 4 + 0] = make_float4(A0.x * inv, A0.y * inv, A0.z * inv, A0.w * inv);
        outr[gl * 4 + 1] = make_float4(A1.x * inv, A1.y * inv, A1.z * inv, A1.w * inv);
        outr[gl * 4 + 2] = make_float4(A2.x * inv, A2.y * inv, A2.z * inv, A2.w * inv);
        outr[gl * 4 + 3] = make_float4(A3.x * inv, A3.y * inv, A3.z * inv, A3.w * inv);
    }
}

// ---------- in-place tanh(neigh @ W) ----------
// 32 rows/block, 16 KB LDS, 4x4 register tile, high occupancy.
__global__ __launch_bounds__(256, 8) void mm_tanh_kernel(const float* __restrict__ W,
                                                         float* __restrict__ nodes, int n_nodes) {
    __shared__ float rows[MMR][H];  // 16 KB
    int t = threadIdx.x;
    int base = blockIdx.x * MMR;
    for (int i = t; i < MMR * (H / 4); i += 256) {
        int r = i >> 5;
        int c4 = i & 31;
        int n = base + r;
        float4 v = make_float4(0.f, 0.f, 0.f, 0.f);
        if (n < n_nodes) v = ((const float4*)(nodes + (size_t)n * H))[c4];
        ((float4*)rows[r])[c4] = v;
    }
    __syncthreads();

    int c0 = (t & 31) * 4;
    int r0 = (t >> 5) * 4;
    float acc[4][4] = {};
    #pragma unroll 2
    for (int k = 0; k < H; k += 4) {
        float4 w0 = *(const float4*)(W + (size_t)(k + 0) * H + c0);
        float4 w1 = *(const float4*)(W + (size_t)(k + 1) * H + c0);
        float4 w2 = *(const float4*)(W + (size_t)(k + 2) * H + c0);
        float4 w3 = *(const float4*)(W + (size_t)(k + 3) * H + c0);
        #pragma unroll
        for (int r = 0; r < 4; ++r) {
            float4 rv = *(const float4*)(&rows[r0 + r][k]);
            acc[r][0] += rv.x * w0.x + rv.y * w1.x + rv.z * w2.x + rv.w * w3.x;
            acc[r][1] += rv.x * w0.y + rv.y * w1.y + rv.z * w2.y + rv.w * w3.y;
            acc[r][2] += rv.x * w0.z + rv.y * w1.z + rv.z * w2.z + rv.w * w3.z;
            acc[r][3] += rv.x * w0.w + rv.y * w1.w + rv.z * w2.w + rv.w * w3.w;
        }
    }
    #pragma unroll
    for (int r = 0; r < 4; ++r) {
        int n = base + r0 + r;
        if (n < n_nodes) {
            float4 o;
            o.x = fast_tanh(acc[r][0]);
            o.y = fast_tanh(acc[r][1]);
            o.z = fast_tanh(acc[r][2]);
            o.w = fast_tanh(acc[r][3]);
            *(float4*)(nodes + (size_t)n * H + c0) = o;
        }
    }
}

extern "C" void kernel_launch(void* const* d_in, const int* in_sizes, int n_in,
                              void* d_out, int out_size, void* d_ws, size_t ws_size,
                              hipStream_t stream) {
    const float* ent = (const float*)d_in[0];
    const float* rel = (const float*)d_in[1];
    const float* W   = (const float*)d_in[2];
    const int* src   = (const int*)d_in[3];
    const int* dst   = (const int*)d_in[4];
    const int* rid   = (const int*)d_in[5];
    int n_nodes = in_sizes[0] / H;
    int n_edges = in_sizes[3];
    float* out = (float*)d_out;

    // ws layout (ints): cnt[N] | cursor[N] | off[N+1] | bsum[BLK] | epack[2E]
    int* cnt    = (int*)d_ws;
    int* cursor = cnt + n_nodes;
    int* off    = cursor + n_nodes;
    int* bsum   = off + n_nodes + 1;
    int2* epack = (int2*)(bsum + BLK);

    int nb1 = (n_nodes + BLK - 1) / BLK;

    hipMemsetAsync(cnt, 0, (size_t)2 * n_nodes * sizeof(int), stream);  // cnt + cursor
    count_kernel<<<(n_edges + BLK - 1) / BLK, BLK, 0, stream>>>(dst, cnt, n_edges);
    blocksum_kernel<<<nb1, BLK, 0, stream>>>(cnt, bsum, n_nodes);
    scanpart_kernel<<<1, BLK, 0, stream>>>(bsum, nb1);
    offsets_kernel<<<nb1, BLK, 0, stream>>>(cnt, bsum, off, n_nodes, n_edges);
    fill_kernel<<<(n_edges + BLK - 1) / BLK, BLK, 0, stream>>>(src, dst, rid, off, cursor, epack, n_edges);

    const int wpb = 4;
    gather_kernel<<<(n_nodes + wpb - 1) / wpb, wpb * 64, 0, stream>>>(ent, rel, epack, off, out, n_nodes);

    mm_tanh_kernel<<<(n_nodes + MMR - 1) / MMR, 256, 0, stream>>>(W, out, n_nodes);
}

// Round 6
// 156.923 us; speedup vs baseline: 1.1042x; 1.1042x over previous
//
#include <hip/hip_runtime.h>
#include <math.h>

#define H 128
#define BLK 256
#define MMR 32  // rows per block in the GEMM pass (16 KB LDS)

__device__ inline float fast_tanh(float x) {
    return 1.0f - 2.0f / (__expf(2.0f * x) + 1.0f);
}

// ---------- CSR build ----------
__global__ void count_kernel(const int* __restrict__ dst, int* __restrict__ cnt, int E) {
    int e = blockIdx.x * blockDim.x + threadIdx.x;
    if (e < E) atomicAdd(&cnt[dst[e]], 1);
}

__global__ void blocksum_kernel(const int* __restrict__ cnt, int* __restrict__ bsum, int n) {
    __shared__ int tmp[BLK];
    int i = blockIdx.x * BLK + threadIdx.x;
    tmp[threadIdx.x] = (i < n) ? cnt[i] : 0;
    __syncthreads();
    for (int d = BLK >> 1; d; d >>= 1) {
        if (threadIdx.x < d) tmp[threadIdx.x] += tmp[threadIdx.x + d];
        __syncthreads();
    }
    if (threadIdx.x == 0) bsum[blockIdx.x] = tmp[0];
}

__global__ void scanpart_kernel(int* bsum, int nb) {
    __shared__ int tmp[BLK];
    int t = threadIdx.x;
    int v = (t < nb) ? bsum[t] : 0;
    tmp[t] = v;
    __syncthreads();
    for (int d = 1; d < BLK; d <<= 1) {
        int add = (t >= d) ? tmp[t - d] : 0;
        __syncthreads();
        tmp[t] += add;
        __syncthreads();
    }
    if (t < nb) bsum[t] = tmp[t] - v;  // exclusive
}

__global__ void offsets_kernel(const int* __restrict__ cnt, const int* __restrict__ bsum,
                               int* __restrict__ off, int n, int E) {
    __shared__ int tmp[BLK];
    int t = threadIdx.x;
    int i = blockIdx.x * BLK + t;
    int v = (i < n) ? cnt[i] : 0;
    tmp[t] = v;
    __syncthreads();
    for (int d = 1; d < BLK; d <<= 1) {
        int add = (t >= d) ? tmp[t - d] : 0;
        __syncthreads();
        tmp[t] += add;
        __syncthreads();
    }
    if (i < n) off[i] = tmp[t] - v + bsum[blockIdx.x];
    if (i == 0) off[n] = E;
}

__global__ void fill_kernel(const int* __restrict__ src, const int* __restrict__ dst,
                            const int* __restrict__ rid, const int* __restrict__ off,
                            int* __restrict__ cursor, int2* __restrict__ epack, int E) {
    int e = blockIdx.x * blockDim.x + threadIdx.x;
    if (e >= E) return;
    int d = dst[e];
    int pos = atomicAdd(&cursor[d], 1);
    epack[off[d] + pos] = make_int2(src[e], rid[e]);
}

// ---------- fused gather: 4 edges in flight per wave, 2-deep pipeline ----------
// wave = 4 groups x 16 lanes; each group owns one edge (8 floats per lane).
// Next edge's rows are loaded before computing the current edge.
__global__ void gather_kernel(const float* __restrict__ ent, const float* __restrict__ rel,
                              const int2* __restrict__ epack, const int* __restrict__ off,
                              float* __restrict__ neigh, int n_nodes) {
    int lane = threadIdx.x & 63;
    int node = blockIdx.x * (blockDim.x >> 6) + (threadIdx.x >> 6);
    if (node >= n_nodes) return;
    int beg = off[node];
    int deg = off[node + 1] - beg;
    int g = lane >> 4;   // group 0..3
    int gl = lane & 15;  // lane within group: float4s gl*2, gl*2+1

    const float4* crow = (const float4*)(ent + (size_t)node * H);
    float4 c0 = crow[gl * 2], c1 = crow[gl * 2 + 1];

    float m = -3.0e38f, s = 0.0f;
    float4 A0 = make_float4(0.f, 0.f, 0.f, 0.f), A1 = A0;

    for (int base = 0; base < deg; base += 64) {
        int chunk = min(64, deg - base);
        int2 my = make_int2(0, 0);
        if (lane < chunk) my = epack[beg + base + lane];
        int iters = (chunk + 3) >> 2;

        // prologue: load this group's first edge
        int k = g;
        bool val = k < chunk;
        int kk = val ? k : 0;
        int sv = __shfl(my.x, kk, 64);
        int rv = __shfl(my.y, kk, 64);
        float4 a0, a1, b0, b1;
        if (val) {
            const float4* ar = (const float4*)(ent + (size_t)sv * H);
            const float4* br = (const float4*)(rel + (size_t)rv * H);
            a0 = ar[gl * 2]; a1 = ar[gl * 2 + 1];
            b0 = br[gl * 2]; b1 = br[gl * 2 + 1];
        }
        for (int i = 0; i < iters; ++i) {
            // issue next edge's loads before computing the current one
            int k2 = k + 4;
            bool val2 = k2 < chunk;
            int kk2 = val2 ? k2 : 0;
            int sv2 = __shfl(my.x, kk2, 64);
            int rv2 = __shfl(my.y, kk2, 64);
            float4 na0, na1, nb0, nb1;
            if (val2) {
                const float4* ar = (const float4*)(ent + (size_t)sv2 * H);
                const float4* br = (const float4*)(rel + (size_t)rv2 * H);
                na0 = ar[gl * 2]; na1 = ar[gl * 2 + 1];
                nb0 = br[gl * 2]; nb1 = br[gl * 2 + 1];
            }
            if (val) {
                float4 q0, q1;
                q0.x = a0.x + b0.x; q0.y = a0.y + b0.y; q0.z = a0.z + b0.z; q0.w = a0.w + b0.w;
                q1.x = a1.x + b1.x; q1.y = a1.y + b1.y; q1.z = a1.z + b1.z; q1.w = a1.w + b1.w;
                float p = q0.x * c0.x + q0.y * c0.y + q0.z * c0.z + q0.w * c0.w
                        + q1.x * c1.x + q1.y * c1.y + q1.z * c1.z + q1.w * c1.w;
                p += __shfl_xor(p, 1, 64);
                p += __shfl_xor(p, 2, 64);
                p += __shfl_xor(p, 4, 64);
                p += __shfl_xor(p, 8, 64);
                if (p > m) {
                    float f = __expf(m - p);
                    s *= f;
                    A0.x *= f; A0.y *= f; A0.z *= f; A0.w *= f;
                    A1.x *= f; A1.y *= f; A1.z *= f; A1.w *= f;
                    m = p;
                }
                float w = __expf(p - m);
                s += w;
                A0.x += q0.x * w; A0.y += q0.y * w; A0.z += q0.z * w; A0.w += q0.w * w;
                A1.x += q1.x * w; A1.y += q1.y * w; A1.z += q1.z * w; A1.w += q1.w * w;
            }
            a0 = na0; a1 = na1; b0 = nb0; b1 = nb1;
            val = val2; k = k2;
        }
    }

    // merge the 4 group states (exact, rescaled); empty groups have m=-3e38,s=0
    #pragma unroll
    for (int xo = 16; xo <= 32; xo <<= 1) {
        float om = __shfl_xor(m, xo, 64);
        float os = __shfl_xor(s, xo, 64);
        float4 o0, o1;
        o0.x = __shfl_xor(A0.x, xo, 64); o0.y = __shfl_xor(A0.y, xo, 64);
        o0.z = __shfl_xor(A0.z, xo, 64); o0.w = __shfl_xor(A0.w, xo, 64);
        o1.x = __shfl_xor(A1.x, xo, 64); o1.y = __shfl_xor(A1.y, xo, 64);
        o1.z = __shfl_xor(A1.z, xo, 64); o1.w = __shfl_xor(A1.w, xo, 64);
        float M = fmaxf(m, om);
        float fs = __expf(m - M), fo = __expf(om - M);
        s = s * fs + os * fo;
        A0.x = A0.x * fs + o0.x * fo; A0.y = A0.y * fs + o0.y * fo;
        A0.z = A0.z * fs + o0.z * fo; A0.w = A0.w * fs + o0.w * fo;
        A1.x = A1.x * fs + o1.x * fo; A1.y = A1.y * fs + o1.y * fo;
        A1.z = A1.z * fs + o1.z * fo; A1.w = A1.w * fs + o1.w * fo;
        m = M;
    }
    float inv = (s > 0.0f) ? 1.0f / s : 0.0f;
    if (g == 0) {
        float4* outr = (float4*)(neigh + (size_t)node * H);
        outr[gl * 2]     = make_float4(A0.x * inv, A0.y * inv, A0.z * inv, A0.w * inv);
        outr[gl * 2 + 1] = make_float4(A1.x * inv, A1.y * inv, A1.z * inv, A1.w * inv);
    }
}

// ---------- in-place tanh(neigh @ W) ----------
// 32 rows/block, 16 KB LDS, 4x4 register tile. (256,4): VGPR cap 128, no spill.
__global__ __launch_bounds__(256, 4) void mm_tanh_kernel(const float* __restrict__ W,
                                                         float* __restrict__ nodes, int n_nodes) {
    __shared__ float rows[MMR][H];  // 16 KB
    int t = threadIdx.x;
    int base = blockIdx.x * MMR;
    for (int i = t; i < MMR * (H / 4); i += 256) {
        int r = i >> 5;
        int c4 = i & 31;
        int n = base + r;
        float4 v = make_float4(0.f, 0.f, 0.f, 0.f);
        if (n < n_nodes) v = ((const float4*)(nodes + (size_t)n * H))[c4];
        ((float4*)rows[r])[c4] = v;
    }
    __syncthreads();

    int c0 = (t & 31) * 4;
    int r0 = (t >> 5) * 4;
    float acc[4][4] = {};
    #pragma unroll 2
    for (int k = 0; k < H; k += 4) {
        float4 w0 = *(const float4*)(W + (size_t)(k + 0) * H + c0);
        float4 w1 = *(const float4*)(W + (size_t)(k + 1) * H + c0);
        float4 w2 = *(const float4*)(W + (size_t)(k + 2) * H + c0);
        float4 w3 = *(const float4*)(W + (size_t)(k + 3) * H + c0);
        #pragma unroll
        for (int r = 0; r < 4; ++r) {
            float4 rv = *(const float4*)(&rows[r0 + r][k]);
            acc[r][0] += rv.x * w0.x + rv.y * w1.x + rv.z * w2.x + rv.w * w3.x;
            acc[r][1] += rv.x * w0.y + rv.y * w1.y + rv.z * w2.y + rv.w * w3.y;
            acc[r][2] += rv.x * w0.z + rv.y * w1.z + rv.z * w2.z + rv.w * w3.z;
            acc[r][3] += rv.x * w0.w + rv.y * w1.w + rv.z * w2.w + rv.w * w3.w;
        }
    }
    #pragma unroll
    for (int r = 0; r < 4; ++r) {
        int n = base + r0 + r;
        if (n < n_nodes) {
            float4 o;
            o.x = fast_tanh(acc[r][0]);
            o.y = fast_tanh(acc[r][1]);
            o.z = fast_tanh(acc[r][2]);
            o.w = fast_tanh(acc[r][3]);
            *(float4*)(nodes + (size_t)n * H + c0) = o;
        }
    }
}

extern "C" void kernel_launch(void* const* d_in, const int* in_sizes, int n_in,
                              void* d_out, int out_size, void* d_ws, size_t ws_size,
                              hipStream_t stream) {
    const float* ent = (const float*)d_in[0];
    const float* rel = (const float*)d_in[1];
    const float* W   = (const float*)d_in[2];
    const int* src   = (const int*)d_in[3];
    const int* dst   = (const int*)d_in[4];
    const int* rid   = (const int*)d_in[5];
    int n_nodes = in_sizes[0] / H;
    int n_edges = in_sizes[3];
    float* out = (float*)d_out;

    // ws layout (ints): cnt[N] | cursor[N] | off[N+1] | bsum[BLK] | epack[2E]
    int* cnt    = (int*)d_ws;
    int* cursor = cnt + n_nodes;
    int* off    = cursor + n_nodes;
    int* bsum   = off + n_nodes + 1;
    int2* epack = (int2*)(bsum + BLK);

    int nb1 = (n_nodes + BLK - 1) / BLK;

    hipMemsetAsync(cnt, 0, (size_t)2 * n_nodes * sizeof(int), stream);  // cnt + cursor
    count_kernel<<<(n_edges + BLK - 1) / BLK, BLK, 0, stream>>>(dst, cnt, n_edges);
    blocksum_kernel<<<nb1, BLK, 0, stream>>>(cnt, bsum, n_nodes);
    scanpart_kernel<<<1, BLK, 0, stream>>>(bsum, nb1);
    offsets_kernel<<<nb1, BLK, 0, stream>>>(cnt, bsum, off, n_nodes, n_edges);
    fill_kernel<<<(n_edges + BLK - 1) / BLK, BLK, 0, stream>>>(src, dst, rid, off, cursor, epack, n_edges);

    const int wpb = 4;
    gather_kernel<<<(n_nodes + wpb - 1) / wpb, wpb * 64, 0, stream>>>(ent, rel, epack, off, out, n_nodes);

    mm_tanh_kernel<<<(n_nodes + MMR - 1) / MMR, 256, 0, stream>>>(W, out, n_nodes);
}

// Round 7
// 154.027 us; speedup vs baseline: 1.1249x; 1.0188x over previous
//
#include <hip/hip_runtime.h>
#include <math.h>

#define H 128
#define BLK 256
#define MMR 32  // rows per block in the GEMM pass (16 KB LDS)

__device__ inline float fast_tanh(float x) {
    return 1.0f - 2.0f / (__expf(2.0f * x) + 1.0f);
}

// ---------- CSR build ----------
__global__ void count_kernel(const int* __restrict__ dst, int* __restrict__ cnt, int E) {
    int e = blockIdx.x * blockDim.x + threadIdx.x;
    if (e < E) atomicAdd(&cnt[dst[e]], 1);
}

// wave-scan allocation of CSR segments (order of segments is arbitrary —
// gather uses off[] + cnt[] so it never needs monotone offsets).
__global__ void alloc_kernel(const int* __restrict__ cnt, int* __restrict__ cursor,
                             int* __restrict__ off, int* __restrict__ total, int n) {
    int i = blockIdx.x * blockDim.x + threadIdx.x;
    int lane = threadIdx.x & 63;
    int v = (i < n) ? cnt[i] : 0;
    int pre = v;
    #pragma unroll
    for (int d = 1; d < 64; d <<= 1) {
        int t = __shfl_up(pre, d, 64);
        if (lane >= d) pre += t;
    }
    int wtot = __shfl(pre, 63, 64);   // wave total
    int wbase = 0;
    if (lane == 63) wbase = atomicAdd(total, wtot);
    wbase = __shfl(wbase, 63, 64);
    int o = wbase + pre - v;          // exclusive within wave + wave base
    if (i < n) { off[i] = o; cursor[i] = o; }
}

__global__ void fill_kernel(const int* __restrict__ src, const int* __restrict__ dst,
                            const int* __restrict__ rid,
                            int* __restrict__ cursor, int2* __restrict__ epack, int E) {
    int e = blockIdx.x * blockDim.x + threadIdx.x;
    if (e >= E) return;
    int d = dst[e];
    int pos = atomicAdd(&cursor[d], 1);  // cursor seeded with off[d]
    epack[pos] = make_int2(src[e], rid[e]);
}

// ---------- fused gather: 2 nodes per wave, 2 subgroups (16 lanes) per node ----------
// Per-subgroup online softmax state; single xo=16 merge stage per node.
__global__ void gather_kernel(const float* __restrict__ ent, const float* __restrict__ rel,
                              const int2* __restrict__ epack, const int* __restrict__ off,
                              const int* __restrict__ cnt,
                              float* __restrict__ neigh, int n_nodes) {
    int lane = threadIdx.x & 63;
    int wid = blockIdx.x * (blockDim.x >> 6) + (threadIdx.x >> 6);
    int half = lane >> 5;            // which node of the pair
    int node = wid * 2 + half;
    bool nvalid = node < n_nodes;
    int nodec = nvalid ? node : 0;
    int sg = (lane >> 4) & 1;        // subgroup within the node
    int gl = lane & 15;              // lane within subgroup: float4s gl*2, gl*2+1

    int beg = off[nodec];
    int deg = nvalid ? cnt[nodec] : 0;
    int degO = __shfl_xor(deg, 32, 64);
    int degM = max(deg, degO);       // wave-uniform loop bound

    const float4* crow = (const float4*)(ent + (size_t)nodec * H);
    float4 c0 = crow[gl * 2], c1 = crow[gl * 2 + 1];

    float m = -3.0e38f, s = 0.0f;
    float4 A0 = make_float4(0.f, 0.f, 0.f, 0.f), A1 = A0;

    for (int base = 0; base < degM; base += 32) {
        int rem = deg - base;        // this half's remaining (may be <=0)
        int2 my = make_int2(0, 0);
        if ((lane & 31) < rem) my = epack[beg + base + (lane & 31)];
        int remM = min(32, degM - base);
        int iters = (remM + 1) >> 1;

        // prologue: this subgroup's first edge of the chunk
        int k = base + sg;
        bool val = k < deg && (k - base) < 32;
        int bl = half * 32 + (val ? (k - base) : 0);
        int sv = __shfl(my.x, bl, 64);
        int rv = __shfl(my.y, bl, 64);
        float4 a0, a1, b0, b1;
        if (val) {
            const float4* ar = (const float4*)(ent + (size_t)sv * H);
            const float4* br = (const float4*)(rel + (size_t)rv * H);
            a0 = ar[gl * 2]; a1 = ar[gl * 2 + 1];
            b0 = br[gl * 2]; b1 = br[gl * 2 + 1];
        }
        for (int it = 0; it < iters; ++it) {
            // issue next edge's index+rows before computing the current one
            int k2 = k + 2;
            bool val2 = k2 < deg && (k2 - base) < 32;
            int bl2 = half * 32 + (val2 ? (k2 - base) : 0);
            int sv2 = __shfl(my.x, bl2, 64);
            int rv2 = __shfl(my.y, bl2, 64);
            float4 na0, na1, nb0, nb1;
            if (val2) {
                const float4* ar = (const float4*)(ent + (size_t)sv2 * H);
                const float4* br = (const float4*)(rel + (size_t)rv2 * H);
                na0 = ar[gl * 2]; na1 = ar[gl * 2 + 1];
                nb0 = br[gl * 2]; nb1 = br[gl * 2 + 1];
            }
            if (val) {
                float4 q0, q1;
                q0.x = a0.x + b0.x; q0.y = a0.y + b0.y; q0.z = a0.z + b0.z; q0.w = a0.w + b0.w;
                q1.x = a1.x + b1.x; q1.y = a1.y + b1.y; q1.z = a1.z + b1.z; q1.w = a1.w + b1.w;
                float p = q0.x * c0.x + q0.y * c0.y + q0.z * c0.z + q0.w * c0.w
                        + q1.x * c1.x + q1.y * c1.y + q1.z * c1.z + q1.w * c1.w;
                // reduce within the 16-lane subgroup
                p += __shfl_xor(p, 1, 64);
                p += __shfl_xor(p, 2, 64);
                p += __shfl_xor(p, 4, 64);
                p += __shfl_xor(p, 8, 64);
                // branchless online-softmax update (exp(0)==1 when no new max)
                float M2 = fmaxf(m, p);
                float f = __expf(m - M2);
                float w = __expf(p - M2);
                m = M2;
                s = s * f + w;
                A0.x = A0.x * f + q0.x * w; A0.y = A0.y * f + q0.y * w;
                A0.z = A0.z * f + q0.z * w; A0.w = A0.w * f + q0.w * w;
                A1.x = A1.x * f + q1.x * w; A1.y = A1.y * f + q1.y * w;
                A1.z = A1.z * f + q1.z * w; A1.w = A1.w * f + q1.w * w;
            }
            a0 = na0; a1 = na1; b0 = nb0; b1 = nb1;
            val = val2; k = k2;
        }
    }

    // single merge stage: subgroup 0 <-> subgroup 1 of the same node
    {
        float om = __shfl_xor(m, 16, 64);
        float os = __shfl_xor(s, 16, 64);
        float4 o0, o1;
        o0.x = __shfl_xor(A0.x, 16, 64); o0.y = __shfl_xor(A0.y, 16, 64);
        o0.z = __shfl_xor(A0.z, 16, 64); o0.w = __shfl_xor(A0.w, 16, 64);
        o1.x = __shfl_xor(A1.x, 16, 64); o1.y = __shfl_xor(A1.y, 16, 64);
        o1.z = __shfl_xor(A1.z, 16, 64); o1.w = __shfl_xor(A1.w, 16, 64);
        float M = fmaxf(m, om);
        float fs = __expf(m - M), fo = __expf(om - M);
        s = s * fs + os * fo;
        A0.x = A0.x * fs + o0.x * fo; A0.y = A0.y * fs + o0.y * fo;
        A0.z = A0.z * fs + o0.z * fo; A0.w = A0.w * fs + o0.w * fo;
        A1.x = A1.x * fs + o1.x * fo; A1.y = A1.y * fs + o1.y * fo;
        A1.z = A1.z * fs + o1.z * fo; A1.w = A1.w * fs + o1.w * fo;
    }
    float inv = (s > 0.0f) ? 1.0f / s : 0.0f;
    if (sg == 0 && nvalid) {
        float4* outr = (float4*)(neigh + (size_t)node * H);
        outr[gl * 2]     = make_float4(A0.x * inv, A0.y * inv, A0.z * inv, A0.w * inv);
        outr[gl * 2 + 1] = make_float4(A1.x * inv, A1.y * inv, A1.z * inv, A1.w * inv);
    }
}

// ---------- in-place tanh(neigh @ W) ----------
__global__ __launch_bounds__(256, 4) void mm_tanh_kernel(const float* __restrict__ W,
                                                         float* __restrict__ nodes, int n_nodes) {
    __shared__ float rows[MMR][H];  // 16 KB
    int t = threadIdx.x;
    int base = blockIdx.x * MMR;
    for (int i = t; i < MMR * (H / 4); i += 256) {
        int r = i >> 5;
        int c4 = i & 31;
        int n = base + r;
        float4 v = make_float4(0.f, 0.f, 0.f, 0.f);
        if (n < n_nodes) v = ((const float4*)(nodes + (size_t)n * H))[c4];
        ((float4*)rows[r])[c4] = v;
    }
    __syncthreads();

    int c0 = (t & 31) * 4;
    int r0 = (t >> 5) * 4;
    float acc[4][4] = {};
    #pragma unroll 2
    for (int k = 0; k < H; k += 4) {
        float4 w0 = *(const float4*)(W + (size_t)(k + 0) * H + c0);
        float4 w1 = *(const float4*)(W + (size_t)(k + 1) * H + c0);
        float4 w2 = *(const float4*)(W + (size_t)(k + 2) * H + c0);
        float4 w3 = *(const float4*)(W + (size_t)(k + 3) * H + c0);
        #pragma unroll
        for (int r = 0; r < 4; ++r) {
            float4 rv = *(const float4*)(&rows[r0 + r][k]);
            acc[r][0] += rv.x * w0.x + rv.y * w1.x + rv.z * w2.x + rv.w * w3.x;
            acc[r][1] += rv.x * w0.y + rv.y * w1.y + rv.z * w2.y + rv.w * w3.y;
            acc[r][2] += rv.x * w0.z + rv.y * w1.z + rv.z * w2.z + rv.w * w3.z;
            acc[r][3] += rv.x * w0.w + rv.y * w1.w + rv.z * w2.w + rv.w * w3.w;
        }
    }
    #pragma unroll
    for (int r = 0; r < 4; ++r) {
        int n = base + r0 + r;
        if (n < n_nodes) {
            float4 o;
            o.x = fast_tanh(acc[r][0]);
            o.y = fast_tanh(acc[r][1]);
            o.z = fast_tanh(acc[r][2]);
            o.w = fast_tanh(acc[r][3]);
            *(float4*)(nodes + (size_t)n * H + c0) = o;
        }
    }
}

extern "C" void kernel_launch(void* const* d_in, const int* in_sizes, int n_in,
                              void* d_out, int out_size, void* d_ws, size_t ws_size,
                              hipStream_t stream) {
    const float* ent = (const float*)d_in[0];
    const float* rel = (const float*)d_in[1];
    const float* W   = (const float*)d_in[2];
    const int* src   = (const int*)d_in[3];
    const int* dst   = (const int*)d_in[4];
    const int* rid   = (const int*)d_in[5];
    int n_nodes = in_sizes[0] / H;
    int n_edges = in_sizes[3];
    float* out = (float*)d_out;

    // ws layout (ints): cnt[N] | total[64 pad] | cursor[N] | off[N] | epack[2E]
    int* cnt    = (int*)d_ws;
    int* total  = cnt + n_nodes;
    int* cursor = total + 64;
    int* off    = cursor + n_nodes;
    int2* epack = (int2*)(off + n_nodes);

    hipMemsetAsync(cnt, 0, (size_t)(n_nodes + 64) * sizeof(int), stream);  // cnt + total
    count_kernel<<<(n_edges + BLK - 1) / BLK, BLK, 0, stream>>>(dst, cnt, n_edges);
    alloc_kernel<<<(n_nodes + BLK - 1) / BLK, BLK, 0, stream>>>(cnt, cursor, off, total, n_nodes);
    fill_kernel<<<(n_edges + BLK - 1) / BLK, BLK, 0, stream>>>(src, dst, rid, cursor, epack, n_edges);

    int n_waves = (n_nodes + 1) / 2;              // 2 nodes per wave
    const int wpb = 4;
    gather_kernel<<<(n_waves + wpb - 1) / wpb, wpb * 64, 0, stream>>>(ent, rel, epack, off, cnt, out, n_nodes);

    mm_tanh_kernel<<<(n_nodes + MMR - 1) / MMR, 256, 0, stream>>>(W, out, n_nodes);
}